// Round 5
// baseline (231.708 us; speedup 1.0000x reference)
//
#include <hip/hip_runtime.h>
#include <cstdint>
#include <cstddef>

// GlobalAttention (Luong 'general'): q = src@W^T ; x = q@MB^T ; softmax(mask) ; c = P@MB
// Outputs: d_out = [ c (8*1024*256) | align_vectors (8*1024*4096) ] fp32.
//
// R5 restructure (flash-style, no x round-trip):
//   k_qproj -> k_fstats (online m/sumexp, NO x store) -> k_stats
//          -> k_pvfused (recompute x, write p once, PV -> fp16 partials) -> k_csum
// Rationale: R3/R4 showed k_logits pinned at ~81 µs across two very different
// occupancy configs; its ~512 MB of L3-tier re-reads at ~6 TB/s is the wall.
// Fixes: (a) eliminate x write+read (268 MB), (b) XCD-aware b=bid%8 mapping so
// each batch's 4 MB mbank slab lives in one XCD's L2, (c) q-fragments in regs.

typedef _Float16 f16;
typedef _Float16 half8 __attribute__((ext_vector_type(8)));
typedef _Float16 half4v __attribute__((ext_vector_type(4)));
typedef float f32x4 __attribute__((ext_vector_type(4)));

#define MFMA16(a, b, c) __builtin_amdgcn_mfma_f32_16x16x32_f16((a), (b), (c), 0, 0, 0)

static constexpr int NBATCH = 8;
static constexpr int NT = 1024;   // TGT
static constexpr int NS = 4096;   // SRC
static constexpr int ND = 256;    // SDIM == TDIM
static constexpr float NEGBIG = -3.0e38f;

// XOR swizzle within an LDS row (bits >=4 only; safe for b16..b128 accesses)
__device__ __forceinline__ int swz(int row, int byteInRow) {
  return byteInRow ^ ((row & 7) << 4);
}

// ---------------- K1: q16 = source @ W^T (fp16 out) ----------------
__global__ __launch_bounds__(256) void k_qproj(const float* __restrict__ src,
                                               const float* __restrict__ W,
                                               f16* __restrict__ q16) {
  __shared__ __align__(16) f16 As[64 * 64];
  __shared__ __align__(16) f16 Bs[256 * 64];
  const int tid = threadIdx.x;
  const int w = tid >> 6, l = tid & 63;
  const int wt = w >> 1, wn = w & 1;
  const int q = l >> 4, lc = l & 15;
  const int t0 = blockIdx.x * 64;

  f32x4 acc[2][8];
#pragma unroll
  for (int i = 0; i < 2; ++i)
#pragma unroll
    for (int j = 0; j < 8; ++j) acc[i][j] = (f32x4){0.f, 0.f, 0.f, 0.f};

  for (int k0 = 0; k0 < 256; k0 += 64) {
    __syncthreads();
    {
      const int r = tid >> 2, c2 = (tid & 3) * 2;
      const float* g = src + (size_t)(t0 + r) * 256 + k0 + c2 * 8;
      float4 f0 = ((const float4*)g)[0], f1 = ((const float4*)g)[1];
      float4 f2 = ((const float4*)g)[2], f3 = ((const float4*)g)[3];
      half8 h0 = {(f16)f0.x, (f16)f0.y, (f16)f0.z, (f16)f0.w,
                  (f16)f1.x, (f16)f1.y, (f16)f1.z, (f16)f1.w};
      half8 h1 = {(f16)f2.x, (f16)f2.y, (f16)f2.z, (f16)f2.w,
                  (f16)f3.x, (f16)f3.y, (f16)f3.z, (f16)f3.w};
      *(half8*)((char*)As + r * 128 + swz(r, c2 * 16)) = h0;
      *(half8*)((char*)As + r * 128 + swz(r, c2 * 16 + 16)) = h1;
    }
    {
      const int n = tid;
      const float* g = W + (size_t)n * 256 + k0;
#pragma unroll
      for (int c = 0; c < 8; ++c) {
        float4 f0 = ((const float4*)(g + c * 8))[0];
        float4 f1 = ((const float4*)(g + c * 8))[1];
        half8 h = {(f16)f0.x, (f16)f0.y, (f16)f0.z, (f16)f0.w,
                   (f16)f1.x, (f16)f1.y, (f16)f1.z, (f16)f1.w};
        *(half8*)((char*)Bs + n * 128 + swz(n, c * 16)) = h;
      }
    }
    __syncthreads();
    half8 a[2][2], bb[8][2];
#pragma unroll
    for (int mb = 0; mb < 2; ++mb)
#pragma unroll
      for (int kf = 0; kf < 2; ++kf) {
        const int r = wt * 32 + mb * 16 + lc;
        a[mb][kf] = *(const half8*)((const char*)As + r * 128 + swz(r, kf * 64 + q * 16));
      }
#pragma unroll
    for (int nb = 0; nb < 8; ++nb)
#pragma unroll
      for (int kf = 0; kf < 2; ++kf) {
        const int r = wn * 128 + nb * 16 + lc;
        bb[nb][kf] = *(const half8*)((const char*)Bs + r * 128 + swz(r, kf * 64 + q * 16));
      }
#pragma unroll
    for (int kf = 0; kf < 2; ++kf)
#pragma unroll
      for (int mb = 0; mb < 2; ++mb)
#pragma unroll
        for (int nb = 0; nb < 8; ++nb)
          acc[mb][nb] = MFMA16(a[mb][kf], bb[nb][kf], acc[mb][nb]);
  }
#pragma unroll
  for (int mb = 0; mb < 2; ++mb)
#pragma unroll
    for (int nb = 0; nb < 8; ++nb)
#pragma unroll
      for (int j = 0; j < 4; ++j) {
        const int t = t0 + wt * 32 + mb * 16 + q * 4 + j;
        const int n = wn * 128 + nb * 16 + lc;
        q16[(size_t)t * 256 + n] = (f16)acc[mb][nb][j];
      }
}

// ---------------- K2: flash stats — x via MFMA, online (m, sumexp), NO x store ----
// flat grid 512: b = bid&7 (XCD-local), sc = (bid>>3)&7 (512-s chunk), tt = bid>>6.
// block 256 (4 waves x 32t), t-tile 128, 8 steps of 64 s. q A-frags in registers.
__global__ __launch_bounds__(256, 3) void k_fstats(const float* __restrict__ mbank,
                                                   const f16* __restrict__ q16,
                                                   const int* __restrict__ mask,
                                                   float* __restrict__ pstats) {
  __shared__ __align__(16) f16 Bs[64 * 256];  // [s][d] f16, 512B rows, swizzled (32 KB)
  const int tid = threadIdx.x;
  const int w = tid >> 6, l = tid & 63;
  const int q = l >> 4, lc = l & 15;
  const int bid = blockIdx.x;
  const int b = bid & 7;
  const int sc = (bid >> 3) & 7;
  const int tt = bid >> 6;
  const int t0 = tt * 128;
  const int s0 = sc * 512;

  // A fragments: this wave's 32 t-rows, full K=256, from q16 (once)
  half8 aq[2][8];
#pragma unroll
  for (int mb = 0; mb < 2; ++mb)
#pragma unroll
    for (int kf = 0; kf < 8; ++kf)
      aq[mb][kf] = *(const half8*)(q16 +
          (size_t)(b * NT + t0 + w * 32 + mb * 16 + lc) * 256 + kf * 32 + q * 8);

  float mrun[8], lrun[8];
#pragma unroll
  for (int i = 0; i < 8; ++i) { mrun[i] = NEGBIG; lrun[i] = 0.f; }

  const int br = tid >> 2;           // Bs staging: row 0..63
  const int cb = (tid & 3) * 64;     // fp32 col base (64 cols per thread)
  for (int st = 0; st < 8; ++st) {
    const int sb = s0 + st * 64;
    __syncthreads();
    {  // stage Bs[64][256] fp32->f16
      const float4* g = (const float4*)(mbank + ((size_t)b * NS + sb + br) * ND + cb);
#pragma unroll
      for (int i = 0; i < 8; ++i) {
        float4 f0 = g[2 * i], f1 = g[2 * i + 1];
        half8 h = {(f16)f0.x, (f16)f0.y, (f16)f0.z, (f16)f0.w,
                   (f16)f1.x, (f16)f1.y, (f16)f1.z, (f16)f1.w};
        *(half8*)((char*)Bs + br * 512 + swz(br, cb * 2 + i * 16)) = h;
      }
    }
    __syncthreads();
    f32x4 xacc[2][4];
#pragma unroll
    for (int i = 0; i < 2; ++i)
#pragma unroll
      for (int j = 0; j < 4; ++j) xacc[i][j] = (f32x4){0.f, 0.f, 0.f, 0.f};
#pragma unroll
    for (int kf = 0; kf < 8; ++kf)
#pragma unroll
      for (int nb = 0; nb < 4; ++nb) {
        const int rs = nb * 16 + lc;
        half8 bb = *(const half8*)((const char*)Bs + rs * 512 + swz(rs, kf * 64 + q * 16));
#pragma unroll
        for (int mb = 0; mb < 2; ++mb)
          xacc[mb][nb] = MFMA16(aq[mb][kf], bb, xacc[mb][nb]);
      }
    bool keep[4];
#pragma unroll
    for (int nb = 0; nb < 4; ++nb)
      keep[nb] = mask[(size_t)b * NS + sb + nb * 16 + lc] != 0;
#pragma unroll
    for (int mb = 0; mb < 2; ++mb)
#pragma unroll
      for (int j = 0; j < 4; ++j) {
        float v[4];
#pragma unroll
        for (int nb = 0; nb < 4; ++nb) v[nb] = keep[nb] ? xacc[mb][nb][j] : NEGBIG;
        float m2 = fmaxf(fmaxf(v[0], v[1]), fmaxf(v[2], v[3]));
#pragma unroll
        for (int d = 1; d < 16; d <<= 1) m2 = fmaxf(m2, __shfl_xor(m2, d));
        float s2 = 0.f;
#pragma unroll
        for (int nb = 0; nb < 4; ++nb) s2 += __expf(v[nb] - m2);
#pragma unroll
        for (int d = 1; d < 16; d <<= 1) s2 += __shfl_xor(s2, d);
        const int idx = mb * 4 + j;
        const float mn = fmaxf(mrun[idx], m2);
        lrun[idx] = lrun[idx] * __expf(mrun[idx] - mn) + s2 * __expf(m2 - mn);
        mrun[idx] = mn;
      }
  }
  if (lc == 0) {
#pragma unroll
    for (int mb = 0; mb < 2; ++mb)
#pragma unroll
      for (int j = 0; j < 4; ++j) {
        const int row = t0 + w * 32 + mb * 16 + q * 4 + j;
        const int idx = mb * 4 + j;
        pstats[(((size_t)b * NT + row) * 8 + sc) * 2 + 0] = mrun[idx];
        pstats[(((size_t)b * NT + row) * 8 + sc) * 2 + 1] = lrun[idx];
      }
  }
}

// ---------------- K3: reduce 8 chunk partials -> m, 1/l per row ----------------
__global__ __launch_bounds__(256) void k_stats(const float* __restrict__ pstats,
                                               float* __restrict__ sm,
                                               float* __restrict__ slinv) {
  const int r = blockIdx.x * 256 + threadIdx.x;  // 0..8191
  const float4* p = (const float4*)(pstats + (size_t)r * 16);
  float4 v[4];
  float mm = NEGBIG;
#pragma unroll
  for (int i = 0; i < 4; ++i) {
    v[i] = p[i];
    mm = fmaxf(mm, fmaxf(v[i].x, v[i].z));
  }
  float ll = 0.f;
#pragma unroll
  for (int i = 0; i < 4; ++i)
    ll += v[i].y * __expf(v[i].x - mm) + v[i].w * __expf(v[i].z - mm);
  sm[r] = mm;
  slinv[r] = (ll > 0.f) ? (1.f / ll) : 0.f;
}

// ---------------- K4: recompute x, p = exp(x-m)/l -> align (once) ; partial c = P@V ----
// flat grid 512: b = bid&7 (XCD-local), kc = (bid>>3)&3 (1024-s chunk), tt = bid>>5.
// block 512 = 8 waves: tg = w>>1 (16t each, t-tile 64) x wd = w&1 (128-d half).
// 16 steps of 64 s: {stage Bs+VT, x=q@Bs^T (regs A), p (mask,exp), store p global,
//  p->Ps LDS} barrier {PV: A from Ps, B from VT}.
__global__ __launch_bounds__(512, 3) void k_pvfused(const float* __restrict__ mbank,
                                                    const f16* __restrict__ q16,
                                                    const int* __restrict__ mask,
                                                    const float* __restrict__ sm,
                                                    const float* __restrict__ slinv,
                                                    float* __restrict__ alignv,
                                                    f16* __restrict__ pc) {
  __shared__ __align__(16) f16 Bs[64 * 256];  // [s][d] 512B rows, swizzled (32 KB)
  __shared__ __align__(16) f16 VT[256 * 64];  // [d][s] 128B rows, swizzled (32 KB)
  __shared__ __align__(16) f16 Ps[64 * 64];   // [t][s] 128B rows, swizzled (8 KB)
  const int tid = threadIdx.x;
  const int w = tid >> 6, l = tid & 63;
  const int tg = w >> 1, wd = w & 1;
  const int q = l >> 4, lc = l & 15;
  const int bid = blockIdx.x;
  const int b = bid & 7;
  const int kc = (bid >> 3) & 3;
  const int tt = bid >> 5;
  const int t0 = tt * 64;
  const int s0 = kc * 1024;

  // A fragments: this wave's 16 t-rows (once)
  half8 aq[8];
#pragma unroll
  for (int kf = 0; kf < 8; ++kf)
    aq[kf] = *(const half8*)(q16 +
        (size_t)(b * NT + t0 + tg * 16 + lc) * 256 + kf * 32 + q * 8);

  float mrowv[4], linvv[4];
#pragma unroll
  for (int j = 0; j < 4; ++j) {
    const size_t rg = (size_t)b * NT + t0 + tg * 16 + q * 4 + j;
    mrowv[j] = sm[rg];
    linvv[j] = slinv[rg];
  }

  f32x4 accC[8];
#pragma unroll
  for (int i = 0; i < 8; ++i) accC[i] = (f32x4){0.f, 0.f, 0.f, 0.f};

  const int br = tid >> 3;              // Bs staging row 0..63
  const int cb = (tid & 7) * 32;        // fp32 col base (32 cols per thread)
  const int dstage = (w & 3) * 64 + l;  // VT row 0..255
  const int shalf = (w >> 2) * 32;      // VT col half

  for (int st = 0; st < 16; ++st) {
    const int sb = s0 + st * 64;
    __syncthreads();  // prev PV done reading Bs/VT/Ps
    {  // stage Bs[64][256]
      const float4* g = (const float4*)(mbank + ((size_t)b * NS + sb + br) * ND + cb);
#pragma unroll
      for (int i = 0; i < 4; ++i) {
        float4 f0 = g[2 * i], f1 = g[2 * i + 1];
        half8 h = {(f16)f0.x, (f16)f0.y, (f16)f0.z, (f16)f0.w,
                   (f16)f1.x, (f16)f1.y, (f16)f1.z, (f16)f1.w};
        *(half8*)((char*)Bs + br * 512 + swz(br, cb * 2 + i * 16)) = h;
      }
    }
    {  // stage VT[256][64] (strided col reads, coalesced across lanes)
#pragma unroll
      for (int i = 0; i < 8; ++i) {
        const int s4 = shalf + i * 4;
        const float* g = mbank + ((size_t)b * NS + sb + s4) * ND + dstage;
        const float f0 = g[0], f1 = g[ND], f2 = g[2 * ND], f3 = g[3 * ND];
        half4v h = {(f16)f0, (f16)f1, (f16)f2, (f16)f3};
        *(half4v*)((char*)VT + dstage * 128 + swz(dstage, s4 * 2)) = h;
      }
    }
    __syncthreads();  // Bs ready (VT/Ps consumed after next barrier)
    // x = q @ mb^T for this wave's 16t x 32s (cols wd*32 .. +32)
    f32x4 xacc[2];
    xacc[0] = (f32x4){0.f, 0.f, 0.f, 0.f};
    xacc[1] = (f32x4){0.f, 0.f, 0.f, 0.f};
#pragma unroll
    for (int kf = 0; kf < 8; ++kf)
#pragma unroll
      for (int nb = 0; nb < 2; ++nb) {
        const int rs = wd * 32 + nb * 16 + lc;
        half8 bb = *(const half8*)((const char*)Bs + rs * 512 + swz(rs, kf * 64 + q * 16));
        xacc[nb] = MFMA16(aq[kf], bb, xacc[nb]);
      }
    // mask -> p -> store global (once per element) + Ps LDS
    bool keepn[2];
#pragma unroll
    for (int nb = 0; nb < 2; ++nb)
      keepn[nb] = mask[(size_t)b * NS + sb + wd * 32 + nb * 16 + lc] != 0;
#pragma unroll
    for (int nb = 0; nb < 2; ++nb)
#pragma unroll
      for (int j = 0; j < 4; ++j) {
        const float pj = keepn[nb] ? __expf(xacc[nb][j] - mrowv[j]) * linvv[j] : 0.f;
        const int tl = tg * 16 + q * 4 + j;
        const int sl = wd * 32 + nb * 16 + lc;
        alignv[((size_t)b * NT + t0 + tl) * NS + sb + sl] = pj;
        *(f16*)((char*)Ps + tl * 128 + swz(tl, sl * 2)) = (f16)pj;
      }
    __syncthreads();  // VT + Ps ready
    // PV: c += P @ V  (A rows = t, K = s64; B = VT cols d)
    half8 apv[2];
#pragma unroll
    for (int kf2 = 0; kf2 < 2; ++kf2) {
      const int rp = tg * 16 + lc;
      apv[kf2] = *(const half8*)((const char*)Ps + rp * 128 + swz(rp, kf2 * 64 + q * 16));
    }
#pragma unroll
    for (int kf2 = 0; kf2 < 2; ++kf2)
#pragma unroll
      for (int nb = 0; nb < 8; ++nb) {
        const int d = wd * 128 + nb * 16 + lc;
        half8 bb = *(const half8*)((const char*)VT + d * 128 + swz(d, kf2 * 64 + q * 16));
        accC[nb] = MFMA16(apv[kf2], bb, accC[nb]);
      }
  }

#pragma unroll
  for (int nb = 0; nb < 8; ++nb)
#pragma unroll
    for (int j = 0; j < 4; ++j) {
      const int t = t0 + tg * 16 + q * 4 + j;
      const int d = wd * 128 + nb * 16 + lc;
      pc[(size_t)kc * ((size_t)NBATCH * NT * ND) + ((size_t)b * NT + t) * ND + d] =
          (f16)accC[nb][j];
    }
}

// ---------------- K5: c = sum of 4 fp16 split-K partials ----------------
__global__ __launch_bounds__(256) void k_csum(const f16* __restrict__ pc,
                                              float* __restrict__ outc) {
  const size_t i8 = ((size_t)blockIdx.x * 256 + threadIdx.x) * 8;
  const size_t STRIDE = (size_t)NBATCH * NT * ND;  // 2097152
  half8 a = *(const half8*)(pc + i8);
  half8 b = *(const half8*)(pc + STRIDE + i8);
  half8 c = *(const half8*)(pc + 2 * STRIDE + i8);
  half8 d = *(const half8*)(pc + 3 * STRIDE + i8);
  float4 r0, r1;
  r0.x = (float)a[0] + (float)b[0] + (float)c[0] + (float)d[0];
  r0.y = (float)a[1] + (float)b[1] + (float)c[1] + (float)d[1];
  r0.z = (float)a[2] + (float)b[2] + (float)c[2] + (float)d[2];
  r0.w = (float)a[3] + (float)b[3] + (float)c[3] + (float)d[3];
  r1.x = (float)a[4] + (float)b[4] + (float)c[4] + (float)d[4];
  r1.y = (float)a[5] + (float)b[5] + (float)c[5] + (float)d[5];
  r1.z = (float)a[6] + (float)b[6] + (float)c[6] + (float)d[6];
  r1.w = (float)a[7] + (float)b[7] + (float)c[7] + (float)d[7];
  *(float4*)(outc + i8) = r0;
  *(float4*)(outc + i8 + 4) = r1;
}

extern "C" void kernel_launch(void* const* d_in, const int* in_sizes, int n_in,
                              void* d_out, int out_size, void* d_ws, size_t ws_size,
                              hipStream_t stream) {
  const float* mbank = (const float*)d_in[0];  // (8,4096,256) f32
  const float* src   = (const float*)d_in[1];  // (8,1024,256) f32
  const int*   mask  = (const int*)d_in[2];    // (8,4096) bool->int
  const float* W     = (const float*)d_in[3];  // (256,256) f32

  float* out_c = (float*)d_out;                         // 2,097,152 f32
  float* out_align = out_c + (size_t)NBATCH * NT * ND;  // 33,554,432 f32

  // ws layout:
  //   [0, 4 MB)        q16   : 8192x256 fp16                (K1 -> K2,K4)
  //   [4 MB, 4.125 MB) pstats: 8192x8x2 f32                 (K2 -> K3)
  //   [5 MB, +32 KB)   sm    : 8192 f32
  //   [5.25 MB,+32 KB) slinv : 8192 f32
  //   [8 MB, 24 MB)    pc    : 4 x 2M fp16 split-K partials (K4 -> K5)
  char* ws = (char*)d_ws;
  f16* q16      = (f16*)ws;
  float* pstats = (float*)(ws + (4 << 20));
  float* sm     = (float*)(ws + (5 << 20));
  float* slinv  = (float*)(ws + (5 << 20) + (256 << 10));
  f16* pc       = (f16*)(ws + (8 << 20));

  hipLaunchKernelGGL(k_qproj, dim3(128), dim3(256), 0, stream, src, W, q16);
  hipLaunchKernelGGL(k_fstats, dim3(512), dim3(256), 0, stream,
                     mbank, q16, mask, pstats);
  hipLaunchKernelGGL(k_stats, dim3(32), dim3(256), 0, stream, pstats, sm, slinv);
  hipLaunchKernelGGL(k_pvfused, dim3(512), dim3(512), 0, stream,
                     mbank, q16, mask, sm, slinv, out_align, pc);
  hipLaunchKernelGGL(k_csum, dim3(1024), dim3(256), 0, stream, pc, out_c);
}